// Round 12
// baseline (270.313 us; speedup 1.0000x reference)
//
#include <hip/hip_runtime.h>
#include <hip/hip_bf16.h>
#include <math.h>

#define N_NODES 50000
#define N_EDGES 600000
#define NFEAT   256
#define NHID    128
#define NCLASS  40
// padded-edge upper bound: E + 7*N (4-byte records)
#define E_PAD_MAX (N_EDGES + 7 * N_NODES)
#define GEMM_BLOCKS  ((N_NODES + 63) / 64)     // 782
#define NBUCK 196            // bucket = dst >> 8 (256-node windows)
#define EPB_A 512            // edges per phase-A block (1172 blocks -> occupancy)
#define BUCK_CAP 4096        // staging capacity per bucket (mean 3072, 18 sigma)

typedef __attribute__((ext_vector_type(8))) short bf16x8;
typedef __attribute__((ext_vector_type(4))) float f32x4;
typedef __attribute__((ext_vector_type(2))) float f32x2;

__device__ inline ushort f2bf(float f) {   // RNE, finite inputs
    uint u = __float_as_uint(f);
    uint r = (u + 0x7fffu + ((u >> 16) & 1u)) >> 16;
    return (ushort)r;
}

// ---------------------------------------------------------------------------
// Phase A: single pass over the edge list. Per-node histogram (for the CSR
// scan) + LDS bucket-binning into fixed-capacity staging regions (b*CAP),
// one global cursor atomic per touched bucket per block. Edge record:
// uint = (bf16(w) << 16) | src.
__global__ __launch_bounds__(256) void scatter_binA(const int* __restrict__ src,
                                                    const int* __restrict__ dst,
                                                    const float* __restrict__ w,
                                                    int* __restrict__ cnt,
                                                    int* __restrict__ bucket_cnt,
                                                    int2* __restrict__ staging, int E) {
    __shared__ int lh[NBUCK];
    int tid = threadIdx.x;
    for (int b = tid; b < NBUCK; b += 256) lh[b] = 0;
    __syncthreads();
    int base = blockIdx.x * EPB_A;
    int d[2];
    #pragma unroll
    for (int j = 0; j < 2; ++j) {
        int i = base + j * 256 + tid;
        d[j] = (i < E) ? dst[i] : -1;
        if (d[j] >= 0) {
            atomicAdd(&cnt[d[j]], 1);        // per-node histogram (for scan)
            atomicAdd(&lh[d[j] >> 8], 1);    // per-bucket count (this block)
        }
    }
    __syncthreads();
    for (int b = tid; b < NBUCK; b += 256) {
        int c = lh[b];
        lh[b] = c ? (b * BUCK_CAP + atomicAdd(&bucket_cnt[b], c)) : 0;
    }
    __syncthreads();
    #pragma unroll
    for (int j = 0; j < 2; ++j) {
        int i = base + j * 256 + tid;
        if (d[j] >= 0) {
            int slot = atomicAdd(&lh[d[j] >> 8], 1);
            uint rec = ((uint)f2bf(w[i]) << 16) | (uint)src[i];
            staging[slot] = make_int2((int)rec, d[j]);
        }
    }
}

// Per-block sums of PADDED counts (blocks < nb); extra blocks convert the
// three weight matrices to transposed bf16 (independent work, one launch).
__global__ __launch_bounds__(256) void scan_bsum_cvtw(const int* __restrict__ cnt,
                                                      int* __restrict__ bsum, int n,
                                                      int nb,
                                                      const float* __restrict__ W1,
                                                      const float* __restrict__ W2,
                                                      const float* __restrict__ W3,
                                                      ushort* __restrict__ BT1,
                                                      ushort* __restrict__ BT2,
                                                      ushort* __restrict__ BT3) {
    if ((int)blockIdx.x >= nb) {
        int idx = ((int)blockIdx.x - nb) * 256 + threadIdx.x;
        if (idx < 32768) {                       // BT1: 128x256 from W1[256x128]
            int nr = idx >> 8, k = idx & 255;
            BT1[idx] = f2bf(W1[(size_t)k * 128 + nr]);
        } else if (idx < 49152) {                // BT2: 128x128 from W2[128x128]
            int t = idx - 32768;
            int nr = t >> 7, k = t & 127;
            BT2[t] = f2bf(W2[(size_t)k * 128 + nr]);
        } else if (idx < 57344) {                // BT3: 64x128 from W3[128x40]
            int t = idx - 49152;
            int nr = t >> 7, k = t & 127;
            BT3[t] = (nr < 40) ? f2bf(W3[(size_t)k * 40 + nr]) : (ushort)0;
        }
        return;
    }
    __shared__ int red[4];
    int i = blockIdx.x * 256 + threadIdx.x;
    int v = (i < n) ? ((cnt[i] + 7) & ~7) : 0;
    #pragma unroll
    for (int off = 32; off; off >>= 1) v += __shfl_down(v, off, 64);
    int wave = threadIdx.x >> 6, lane = threadIdx.x & 63;
    if (lane == 0) red[wave] = v;
    __syncthreads();
    if (threadIdx.x == 0) bsum[blockIdx.x] = red[0] + red[1] + red[2] + red[3];
}

// Merged scan_final + phase-B scatter. One block per bucket (= per scan
// block of 256 nodes): computes rsp for its nodes (block offset from bsum),
// keeps CSR cursors in LDS, zeroes its CSR window (covers padding slots),
// then streams the bucket's staging region and scatters records via LDS
// cursor atomics — no global cursor array, writes confined to the bucket's
// ~17KB window.
__global__ __launch_bounds__(256) void scan_scatter(const int* __restrict__ cnt,
                                                    const int* __restrict__ bsum,
                                                    const int* __restrict__ bucket_cnt,
                                                    const int2* __restrict__ staging,
                                                    int* __restrict__ rsp,
                                                    uint* __restrict__ edges, int n) {
    __shared__ int buf[256];
    __shared__ int lcur[256];
    __shared__ int boff_s;
    int tid = threadIdx.x;
    if (tid < 64) {
        int s = 0;
        for (int i = tid; i < (int)blockIdx.x; i += 64) s += bsum[i];
        #pragma unroll
        for (int off = 32; off; off >>= 1) s += __shfl_down(s, off, 64);
        if (tid == 0) boff_s = s;
    }
    int i = blockIdx.x * 256 + tid;
    int v = (i < n) ? ((cnt[i] + 7) & ~7) : 0;
    buf[tid] = v;
    __syncthreads();
    #pragma unroll
    for (int off = 1; off < 256; off <<= 1) {
        int t = (tid >= off) ? buf[tid - off] : 0;
        __syncthreads();
        buf[tid] += t;
        __syncthreads();
    }
    int ex = buf[tid] - v + boff_s;
    if (i < n) rsp[i] = ex;
    if (i == n - 1) rsp[n] = ex + v;
    lcur[tid] = ex;
    __syncthreads();
    // zero this bucket's CSR window (incl. padding slots)
    int s0 = boff_s;
    int e0 = buf[255] + boff_s;   // inclusive-scan total + offset
    for (int p = s0 + tid; p < e0; p += 256) edges[p] = 0;
    __syncthreads();
    // scatter from staging
    int c = bucket_cnt[blockIdx.x];
    const int2* st = staging + (size_t)blockIdx.x * BUCK_CAP;
    for (int p = tid; p < c; p += 256) {
        int2 r = st[p];
        int slot = atomicAdd(&lcur[r.y & 255], 1);
        edges[slot] = (uint)r.x;
    }
}

// ---------------------------------------------------------------------------
// bf16 MFMA GEMM body: C[M x Nout] = A[M x K] @ BT[.. x K]^T, one 64-row tile.
// AF32: A is fp32 in global; converted to bf16 during LDS staging (fused cvt).
template<int NT, bool OUTBF, bool AF32>
__device__ __forceinline__ void gemm_body(const void* __restrict__ Ain,
                                          const ushort* __restrict__ BT,
                                          int M, int K, int Nout,
                                          void* __restrict__ Cout, int row0) {
    __shared__ ushort a_s[64 * 40];
    __shared__ ushort b_s[64 * NT * 40];
    int tid = threadIdx.x;
    int wave = tid >> 6, lane = tid & 63;
    int lr = lane & 15, lk = (lane >> 4) * 8;
    f32x4 acc[4][NT];
    #pragma unroll
    for (int mt = 0; mt < 4; ++mt)
        #pragma unroll
        for (int nt = 0; nt < NT; ++nt) acc[mt][nt] = (f32x4){0.f, 0.f, 0.f, 0.f};

    for (int k0 = 0; k0 < K; k0 += 32) {
        {   // A tile: 64 rows x 32 k, 8 elems/thread
            int r = tid >> 2, c8 = (tid & 3) * 8;
            int gr = row0 + r; if (gr >= M) gr = M - 1;  // clamp, store-guarded
            if (AF32) {
                const float* Af = (const float*)Ain;
                float4 v0 = *(const float4*)(Af + (size_t)gr * K + k0 + c8);
                float4 v1 = *(const float4*)(Af + (size_t)gr * K + k0 + c8 + 4);
                ushort4 o0, o1;
                o0.x = f2bf(v0.x); o0.y = f2bf(v0.y); o0.z = f2bf(v0.z); o0.w = f2bf(v0.w);
                o1.x = f2bf(v1.x); o1.y = f2bf(v1.y); o1.z = f2bf(v1.z); o1.w = f2bf(v1.w);
                *(ushort4*)(a_s + r * 40 + c8) = o0;
                *(ushort4*)(a_s + r * 40 + c8 + 4) = o1;
            } else {
                const ushort* Ab = (const ushort*)Ain;
                float4 v = *(const float4*)(Ab + (size_t)gr * K + k0 + c8);
                *(float4*)(a_s + r * 40 + c8) = v;
            }
        }
        #pragma unroll
        for (int i = 0; i < NT; ++i) {  // BT tile: 64*NT rows x 32 k
            int idx = tid * NT + i;
            int r = idx >> 2, c8 = (idx & 3) * 8;
            float4 v = *(const float4*)(BT + (size_t)r * K + k0 + c8);
            *(float4*)(b_s + r * 40 + c8) = v;
        }
        __syncthreads();
        bf16x8 bfr[NT];
        #pragma unroll
        for (int nt = 0; nt < NT; ++nt)
            bfr[nt] = *(const bf16x8*)(b_s + ((wave * NT + nt) * 16 + lr) * 40 + lk);
        #pragma unroll
        for (int mt = 0; mt < 4; ++mt) {
            bf16x8 afr = *(const bf16x8*)(a_s + (mt * 16 + lr) * 40 + lk);
            #pragma unroll
            for (int nt = 0; nt < NT; ++nt)
                acc[mt][nt] = __builtin_amdgcn_mfma_f32_16x16x32_bf16(
                    afr, bfr[nt], acc[mt][nt], 0, 0, 0);
        }
        __syncthreads();
    }
    // C/D layout: col = lane&15, row = (lane>>4)*4 + i
    int col0 = wave * NT * 16;
    #pragma unroll
    for (int mt = 0; mt < 4; ++mt) {
        int gr0 = row0 + mt * 16 + (lane >> 4) * 4;
        #pragma unroll
        for (int nt = 0; nt < NT; ++nt) {
            int gc = col0 + nt * 16 + lr;
            #pragma unroll
            for (int i = 0; i < 4; ++i) {
                int gr = gr0 + i;
                if (gr < M && gc < Nout) {
                    if (OUTBF)
                        ((ushort*)Cout)[(size_t)gr * Nout + gc] = f2bf(acc[mt][nt][i]);
                    else
                        ((float*)Cout)[(size_t)gr * Nout + gc] = acc[mt][nt][i];
                }
            }
        }
    }
}

template<int NT, bool OUTBF, bool AF32>
__global__ __launch_bounds__(256) void gemm_mfma(const void* __restrict__ Ain,
                                                 const ushort* __restrict__ BT,
                                                 int M, int K, int Nout,
                                                 void* __restrict__ Cout) {
    gemm_body<NT, OUTBF, AF32>(Ain, BT, M, K, Nout, Cout, blockIdx.x * 64);
}

// ---------------------------------------------------------------------------
// SpMM over bf16 support. Padded CSR, 4B records: rec = (bf16(w)<<16) | src.
// Branch-free 8-edge groups, record rotate-prefetch, f32x2 accumulator so the
// two features FMA via one v_pk_fma_f32 per edge.
__global__ __launch_bounds__(256) void spmm128b(const uint* __restrict__ sup,
                                                const int* __restrict__ rsp,
                                                const uint* __restrict__ edges,
                                                const float* __restrict__ bias,
                                                uint* __restrict__ outb, int n) {
    int wid = blockIdx.x * 4 + (threadIdx.x >> 6);
    int lane = threadIdx.x & 63;
    if (wid >= n) return;
    int k = rsp[wid], e = rsp[wid + 1];
    f32x2 acc = (f32x2){0.f, 0.f};
    if (k < e) {
        const uint4* q4 = (const uint4*)(edges + k);
        uint4 qa = q4[0], qb = q4[1];
        for (; k < e; k += 8) {
            int kn = k + 8;
            int kc = (kn < e) ? kn : k;          // clamp: reload current (L1 hit)
            const uint4* n4 = (const uint4*)(edges + kc);
            uint4 na = n4[0], nb = n4[1];        // prefetch next group
            uint q[8] = {qa.x, qa.y, qa.z, qa.w, qb.x, qb.y, qb.z, qb.w};
            uint p[8];
            #pragma unroll
            for (int j = 0; j < 8; ++j)
                p[j] = sup[(size_t)(q[j] & 0xffffu) * 64 + lane];
            #pragma unroll
            for (int j = 0; j < 8; ++j) {
                float w = __uint_as_float(q[j] & 0xffff0000u);  // bf16 bits -> f32
                f32x2 v;
                v.x = __uint_as_float(p[j] << 16);
                v.y = __uint_as_float(p[j] & 0xffff0000u);
                acc += v * (f32x2){w, w};
            }
            qa = na; qb = nb;
        }
    }
    float ax = fmaxf(acc.x + bias[lane * 2], 0.f);
    float ay = fmaxf(acc.y + bias[lane * 2 + 1], 0.f);
    outb[(size_t)wid * 64 + lane] = ((uint)f2bf(ay) << 16) | (uint)f2bf(ax);
}

// Layer 3: bf16 F=40 segment-sum + bias + log_softmax fused -> d_out (fp32)
__global__ __launch_bounds__(256) void spmm40_lsm(const ushort* __restrict__ sup,
                                                  const int* __restrict__ rsp,
                                                  const uint* __restrict__ edges,
                                                  const float* __restrict__ bias,
                                                  float* __restrict__ out, int n) {
    int wid = blockIdx.x * 4 + (threadIdx.x >> 6);
    int lane = threadIdx.x & 63;
    if (wid >= n) return;
    int k = rsp[wid], e = rsp[wid + 1];
    float acc = 0.f;
    int lf = (lane < 40) ? lane : 39;  // inactive lanes read lane 39 (no OOB)
    if (k < e) {
        const uint4* q4 = (const uint4*)(edges + k);
        uint4 qa = q4[0], qb = q4[1];
        for (; k < e; k += 8) {
            int kn = k + 8;
            int kc = (kn < e) ? kn : k;
            const uint4* n4 = (const uint4*)(edges + kc);
            uint4 na = n4[0], nb = n4[1];
            uint q[8] = {qa.x, qa.y, qa.z, qa.w, qb.x, qb.y, qb.z, qb.w};
            float p[8];
            #pragma unroll
            for (int j = 0; j < 8; ++j) {
                uint us = sup[(size_t)(q[j] & 0xffffu) * 40 + lf];
                p[j] = __uint_as_float(us << 16);
            }
            #pragma unroll
            for (int j = 0; j < 8; ++j)
                acc += p[j] * __uint_as_float(q[j] & 0xffff0000u);
            qa = na; qb = nb;
        }
    }
    float v = (lane < 40) ? acc + bias[lane] : -INFINITY;
    float m = v;
    #pragma unroll
    for (int off = 32; off; off >>= 1) m = fmaxf(m, __shfl_xor(m, off, 64));
    float ex = (lane < 40) ? expf(v - m) : 0.f;
    float s = ex;
    #pragma unroll
    for (int off = 32; off; off >>= 1) s += __shfl_xor(s, off, 64);
    float ls = logf(s);
    if (lane < 40) out[(size_t)wid * 40 + lane] = v - m - ls;
}

// ---------------------------------------------------------------------------
extern "C" void kernel_launch(void* const* d_in, const int* in_sizes, int n_in,
                              void* d_out, int out_size, void* d_ws, size_t ws_size,
                              hipStream_t stream) {
    const float* x   = (const float*)d_in[0];
    const float* ew  = (const float*)d_in[1];
    const float* W1  = (const float*)d_in[2];
    const float* b1  = (const float*)d_in[3];
    const float* W2  = (const float*)d_in[4];
    const float* b2  = (const float*)d_in[5];
    const float* W3  = (const float*)d_in[6];
    const float* b3  = (const float*)d_in[7];
    const int* esrc  = (const int*)d_in[8];
    const int* edst  = (const int*)d_in[9];
    float* out = (float*)d_out;

    char* ws = (char*)d_ws;
    size_t off = 0;
    auto alloc = [&](size_t bytes) {
        size_t cur = off;
        off += (bytes + 255) & ~(size_t)255;
        return cur;
    };
    // cnt + bucket_cnt contiguous -> one memset covers both
    int* cnt        = (int*)(ws + alloc((N_NODES + 1 + 256) * sizeof(int)));
    int* bucket_cnt = cnt + N_NODES + 1;
    int* rsp     = (int*)(ws + alloc((N_NODES + 1) * sizeof(int)));
    int* bsum    = (int*)(ws + alloc(256 * sizeof(int)));
    uint* edges  = (uint*)(ws + alloc((size_t)E_PAD_MAX * sizeof(uint)));      // 3.8 MB
    int2* staging = (int2*)(ws + alloc((size_t)NBUCK * BUCK_CAP * sizeof(int2))); // 6.4 MB
    ushort* BT1  = (ushort*)(ws + alloc(128 * 256 * 2));
    ushort* BT2  = (ushort*)(ws + alloc(128 * 128 * 2));
    ushort* BT3  = (ushort*)(ws + alloc(64 * 128 * 2));
    char* Sreg   = ws + alloc((size_t)N_NODES * 128 * 2);       // 12.8 MB
    char* Hreg   = ws + alloc((size_t)N_NODES * 128 * 2);       // 12.8 MB
    char* Treg   = ws + alloc((size_t)N_NODES * 128 * 2);       // 12.8 MB

    ushort* supA = (ushort*)Sreg;                  // gemm1 out
    ushort* hA   = (ushort*)Hreg;                  // spmm1 out
    ushort* supB = (ushort*)Treg;                  // gemm2 out
    ushort* hB   = (ushort*)Sreg;                  // spmm2 out (supA dead)
    ushort* sup3 = (ushort*)Treg;                  // gemm3 out bf16 (supB dead)

    int scan_blocks = (N_NODES + 255) / 256;  // 196 == NBUCK
    int cvtw_blocks = (57344 + 255) / 256;    // 224

    // --- CSR build: memset, binA (hist+bin), scan(+cvtw), scan_scatter ---
    hipMemsetAsync(cnt, 0, (N_NODES + 1 + 256) * sizeof(int), stream);
    scatter_binA<<<(N_EDGES + EPB_A - 1) / EPB_A, 256, 0, stream>>>(
        esrc, edst, ew, cnt, bucket_cnt, staging, N_EDGES);
    scan_bsum_cvtw<<<scan_blocks + cvtw_blocks, 256, 0, stream>>>(
        cnt, bsum, N_NODES, scan_blocks, W1, W2, W3, BT1, BT2, BT3);
    scan_scatter<<<NBUCK, 256, 0, stream>>>(cnt, bsum, bucket_cnt, staging, rsp,
                                            edges, N_NODES);

    int spmm_blocks = (N_NODES + 3) / 4;     // 12500

    // --- layer 1 (x fp32 converted in gemm staging) ---
    gemm_mfma<2, true, true><<<GEMM_BLOCKS, 256, 0, stream>>>(x, BT1, N_NODES, 256,
                                                              128, supA);
    spmm128b<<<spmm_blocks, 256, 0, stream>>>((const uint*)supA, rsp, edges, b1,
                                              (uint*)hA, N_NODES);
    // --- layer 2 ---
    gemm_mfma<2, true, false><<<GEMM_BLOCKS, 256, 0, stream>>>(hA, BT2, N_NODES, 128,
                                                               128, supB);
    spmm128b<<<spmm_blocks, 256, 0, stream>>>((const uint*)supB, rsp, edges, b2,
                                              (uint*)hB, N_NODES);
    // --- layer 3 ---
    gemm_mfma<1, true, false><<<GEMM_BLOCKS, 256, 0, stream>>>(hB, BT3, N_NODES, 128,
                                                               40, sup3);
    spmm40_lsm<<<spmm_blocks, 256, 0, stream>>>(sup3, rsp, edges, b3, out, N_NODES);
}

// Round 13
// 233.083 us; speedup vs baseline: 1.1597x; 1.1597x over previous
//
#include <hip/hip_runtime.h>
#include <hip/hip_bf16.h>
#include <math.h>

#define N_NODES 50000
#define N_EDGES 600000
#define NFEAT   256
#define NHID    128
#define NCLASS  40
// padded-edge upper bound: E + 7*N (4-byte records)
#define E_PAD_MAX (N_EDGES + 7 * N_NODES)
#define GEMM_BLOCKS  ((N_NODES + 63) / 64)     // 782
#define NBUCK 196            // bucket = dst >> 8 (256-node windows)
#define EPB_A 2048           // edges per phase-A block (bigger chunks -> merge)
#define BUCK_CAP 4096        // staging capacity per bucket (mean 3072)

typedef __attribute__((ext_vector_type(8))) short bf16x8;
typedef __attribute__((ext_vector_type(4))) float f32x4;
typedef __attribute__((ext_vector_type(2))) float f32x2;

__device__ inline ushort f2bf(float f) {   // RNE, finite inputs
    uint u = __float_as_uint(f);
    uint r = (u + 0x7fffu + ((u >> 16) & 1u)) >> 16;
    return (ushort)r;
}

// ---------------------------------------------------------------------------
// Phase A: bin edges by 256-node bucket into fixed-capacity staging regions.
// NO per-node global atomics — per-node counts are recomputed bucket-locally
// later from the staged records. Record: uint = (bf16(w)<<16) | src;
// staging entry = {rec, dst & 255}.
__global__ __launch_bounds__(256) void scatter_binA(const int* __restrict__ src,
                                                    const int* __restrict__ dst,
                                                    const float* __restrict__ w,
                                                    int* __restrict__ bucket_cnt,
                                                    int2* __restrict__ staging, int E) {
    __shared__ int lh[NBUCK];
    int tid = threadIdx.x;
    for (int b = tid; b < NBUCK; b += 256) lh[b] = 0;
    __syncthreads();
    int base = blockIdx.x * EPB_A;
    int d[8];
    #pragma unroll
    for (int j = 0; j < 8; ++j) {
        int i = base + j * 256 + tid;
        d[j] = (i < E) ? dst[i] : -1;
        if (d[j] >= 0) atomicAdd(&lh[d[j] >> 8], 1);
    }
    __syncthreads();
    for (int b = tid; b < NBUCK; b += 256) {
        int c = lh[b];
        lh[b] = c ? (b * BUCK_CAP + atomicAdd(&bucket_cnt[b], c)) : 0;
    }
    __syncthreads();
    #pragma unroll
    for (int j = 0; j < 8; ++j) {
        int i = base + j * 256 + tid;
        if (d[j] >= 0) {
            int slot = atomicAdd(&lh[d[j] >> 8], 1);
            uint rec = ((uint)f2bf(w[i]) << 16) | (uint)src[i];
            staging[slot] = make_int2((int)rec, d[j] & 255);
        }
    }
}

// Per-bucket padded totals (bsum) from staging via LDS histogram (blocks
// < nb); extra blocks convert the three weight matrices to transposed bf16.
__global__ __launch_bounds__(256) void bucket_hist_cvtw(const int* __restrict__ bucket_cnt,
                                                        const int2* __restrict__ staging,
                                                        int* __restrict__ bsum, int nb,
                                                        const float* __restrict__ W1,
                                                        const float* __restrict__ W2,
                                                        const float* __restrict__ W3,
                                                        ushort* __restrict__ BT1,
                                                        ushort* __restrict__ BT2,
                                                        ushort* __restrict__ BT3) {
    if ((int)blockIdx.x >= nb) {
        int idx = ((int)blockIdx.x - nb) * 256 + threadIdx.x;
        if (idx < 32768) {                       // BT1: 128x256 from W1[256x128]
            int nr = idx >> 8, k = idx & 255;
            BT1[idx] = f2bf(W1[(size_t)k * 128 + nr]);
        } else if (idx < 49152) {                // BT2: 128x128 from W2[128x128]
            int t = idx - 32768;
            int nr = t >> 7, k = t & 127;
            BT2[t] = f2bf(W2[(size_t)k * 128 + nr]);
        } else if (idx < 57344) {                // BT3: 64x128 from W3[128x40]
            int t = idx - 49152;
            int nr = t >> 7, k = t & 127;
            BT3[t] = (nr < 40) ? f2bf(W3[(size_t)k * 40 + nr]) : (ushort)0;
        }
        return;
    }
    __shared__ int hist[256];
    __shared__ int red[4];
    int tid = threadIdx.x;
    hist[tid] = 0;
    __syncthreads();
    int b = blockIdx.x;
    int c = bucket_cnt[b];
    const int2* st = staging + (size_t)b * BUCK_CAP;
    for (int p = tid; p < c; p += 256) atomicAdd(&hist[st[p].y], 1);
    __syncthreads();
    int v = (hist[tid] + 7) & ~7;   // padded per-node count
    #pragma unroll
    for (int off = 32; off; off >>= 1) v += __shfl_down(v, off, 64);
    int wv = tid >> 6, lane = tid & 63;
    if (lane == 0) red[wv] = v;
    __syncthreads();
    if (tid == 0) bsum[b] = red[0] + red[1] + red[2] + red[3];
}

// Merged scan + scatter, one block per bucket: rebuild per-node counts from
// staging (LDS hist), block offset from bsum prefix, in-block exclusive scan,
// zero the bucket's CSR window (covers padding), scatter via LDS cursors.
// All CSR writes confined to the bucket's ~17KB window.
__global__ __launch_bounds__(256) void scan_scatter(const int* __restrict__ bsum,
                                                    const int* __restrict__ bucket_cnt,
                                                    const int2* __restrict__ staging,
                                                    int* __restrict__ rsp,
                                                    uint* __restrict__ edges, int n) {
    __shared__ int hist[256];
    __shared__ int buf[256];
    __shared__ int lcur[256];
    __shared__ int boff_s;
    int tid = threadIdx.x;
    hist[tid] = 0;
    if (tid < 64) {
        int s = 0;
        for (int i = tid; i < (int)blockIdx.x; i += 64) s += bsum[i];
        #pragma unroll
        for (int off = 32; off; off >>= 1) s += __shfl_down(s, off, 64);
        if (tid == 0) boff_s = s;
    }
    __syncthreads();
    int b = blockIdx.x;
    int c = bucket_cnt[b];
    const int2* st = staging + (size_t)b * BUCK_CAP;
    for (int p = tid; p < c; p += 256) atomicAdd(&hist[st[p].y], 1);
    __syncthreads();
    int v = (hist[tid] + 7) & ~7;
    buf[tid] = v;
    __syncthreads();
    #pragma unroll
    for (int off = 1; off < 256; off <<= 1) {
        int t = (tid >= off) ? buf[tid - off] : 0;
        __syncthreads();
        buf[tid] += t;
        __syncthreads();
    }
    int ex = buf[tid] - v + boff_s;
    int i = b * 256 + tid;
    if (i < n) rsp[i] = ex;
    if (i == n - 1) rsp[n] = ex + v;
    lcur[tid] = ex;
    __syncthreads();
    int s0 = boff_s, e0 = buf[255] + boff_s;
    for (int p = s0 + tid; p < e0; p += 256) edges[p] = 0;
    __syncthreads();
    for (int p = tid; p < c; p += 256) {
        int2 r = st[p];
        int slot = atomicAdd(&lcur[r.y], 1);
        edges[slot] = (uint)r.x;
    }
}

// ---------------------------------------------------------------------------
// bf16 MFMA GEMM body: C[M x Nout] = A[M x K] @ BT[.. x K]^T, one 64-row tile.
// AF32: A is fp32 in global; converted to bf16 during LDS staging (fused cvt).
template<int NT, bool OUTBF, bool AF32>
__device__ __forceinline__ void gemm_body(const void* __restrict__ Ain,
                                          const ushort* __restrict__ BT,
                                          int M, int K, int Nout,
                                          void* __restrict__ Cout, int row0) {
    __shared__ ushort a_s[64 * 40];
    __shared__ ushort b_s[64 * NT * 40];
    int tid = threadIdx.x;
    int wave = tid >> 6, lane = tid & 63;
    int lr = lane & 15, lk = (lane >> 4) * 8;
    f32x4 acc[4][NT];
    #pragma unroll
    for (int mt = 0; mt < 4; ++mt)
        #pragma unroll
        for (int nt = 0; nt < NT; ++nt) acc[mt][nt] = (f32x4){0.f, 0.f, 0.f, 0.f};

    for (int k0 = 0; k0 < K; k0 += 32) {
        {   // A tile: 64 rows x 32 k, 8 elems/thread
            int r = tid >> 2, c8 = (tid & 3) * 8;
            int gr = row0 + r; if (gr >= M) gr = M - 1;  // clamp, store-guarded
            if (AF32) {
                const float* Af = (const float*)Ain;
                float4 v0 = *(const float4*)(Af + (size_t)gr * K + k0 + c8);
                float4 v1 = *(const float4*)(Af + (size_t)gr * K + k0 + c8 + 4);
                ushort4 o0, o1;
                o0.x = f2bf(v0.x); o0.y = f2bf(v0.y); o0.z = f2bf(v0.z); o0.w = f2bf(v0.w);
                o1.x = f2bf(v1.x); o1.y = f2bf(v1.y); o1.z = f2bf(v1.z); o1.w = f2bf(v1.w);
                *(ushort4*)(a_s + r * 40 + c8) = o0;
                *(ushort4*)(a_s + r * 40 + c8 + 4) = o1;
            } else {
                const ushort* Ab = (const ushort*)Ain;
                float4 v = *(const float4*)(Ab + (size_t)gr * K + k0 + c8);
                *(float4*)(a_s + r * 40 + c8) = v;
            }
        }
        #pragma unroll
        for (int i = 0; i < NT; ++i) {  // BT tile: 64*NT rows x 32 k
            int idx = tid * NT + i;
            int r = idx >> 2, c8 = (idx & 3) * 8;
            float4 v = *(const float4*)(BT + (size_t)r * K + k0 + c8);
            *(float4*)(b_s + r * 40 + c8) = v;
        }
        __syncthreads();
        bf16x8 bfr[NT];
        #pragma unroll
        for (int nt = 0; nt < NT; ++nt)
            bfr[nt] = *(const bf16x8*)(b_s + ((wave * NT + nt) * 16 + lr) * 40 + lk);
        #pragma unroll
        for (int mt = 0; mt < 4; ++mt) {
            bf16x8 afr = *(const bf16x8*)(a_s + (mt * 16 + lr) * 40 + lk);
            #pragma unroll
            for (int nt = 0; nt < NT; ++nt)
                acc[mt][nt] = __builtin_amdgcn_mfma_f32_16x16x32_bf16(
                    afr, bfr[nt], acc[mt][nt], 0, 0, 0);
        }
        __syncthreads();
    }
    // C/D layout: col = lane&15, row = (lane>>4)*4 + i
    int col0 = wave * NT * 16;
    #pragma unroll
    for (int mt = 0; mt < 4; ++mt) {
        int gr0 = row0 + mt * 16 + (lane >> 4) * 4;
        #pragma unroll
        for (int nt = 0; nt < NT; ++nt) {
            int gc = col0 + nt * 16 + lr;
            #pragma unroll
            for (int i = 0; i < 4; ++i) {
                int gr = gr0 + i;
                if (gr < M && gc < Nout) {
                    if (OUTBF)
                        ((ushort*)Cout)[(size_t)gr * Nout + gc] = f2bf(acc[mt][nt][i]);
                    else
                        ((float*)Cout)[(size_t)gr * Nout + gc] = acc[mt][nt][i];
                }
            }
        }
    }
}

template<int NT, bool OUTBF, bool AF32>
__global__ __launch_bounds__(256) void gemm_mfma(const void* __restrict__ Ain,
                                                 const ushort* __restrict__ BT,
                                                 int M, int K, int Nout,
                                                 void* __restrict__ Cout) {
    gemm_body<NT, OUTBF, AF32>(Ain, BT, M, K, Nout, Cout, blockIdx.x * 64);
}

// ---------------------------------------------------------------------------
// SpMM over bf16 support. Padded CSR, 4B records: rec = (bf16(w)<<16) | src.
// Branch-free 8-edge groups, record rotate-prefetch, f32x2 accumulator so the
// two features FMA via one v_pk_fma_f32 per edge.
__global__ __launch_bounds__(256) void spmm128b(const uint* __restrict__ sup,
                                                const int* __restrict__ rsp,
                                                const uint* __restrict__ edges,
                                                const float* __restrict__ bias,
                                                uint* __restrict__ outb, int n) {
    int wid = blockIdx.x * 4 + (threadIdx.x >> 6);
    int lane = threadIdx.x & 63;
    if (wid >= n) return;
    int k = rsp[wid], e = rsp[wid + 1];
    f32x2 acc = (f32x2){0.f, 0.f};
    if (k < e) {
        const uint4* q4 = (const uint4*)(edges + k);
        uint4 qa = q4[0], qb = q4[1];
        for (; k < e; k += 8) {
            int kn = k + 8;
            int kc = (kn < e) ? kn : k;          // clamp: reload current (L1 hit)
            const uint4* n4 = (const uint4*)(edges + kc);
            uint4 na = n4[0], nb = n4[1];        // prefetch next group
            uint q[8] = {qa.x, qa.y, qa.z, qa.w, qb.x, qb.y, qb.z, qb.w};
            uint p[8];
            #pragma unroll
            for (int j = 0; j < 8; ++j)
                p[j] = sup[(size_t)(q[j] & 0xffffu) * 64 + lane];
            #pragma unroll
            for (int j = 0; j < 8; ++j) {
                float w = __uint_as_float(q[j] & 0xffff0000u);  // bf16 bits -> f32
                f32x2 v;
                v.x = __uint_as_float(p[j] << 16);
                v.y = __uint_as_float(p[j] & 0xffff0000u);
                acc += v * (f32x2){w, w};
            }
            qa = na; qb = nb;
        }
    }
    float ax = fmaxf(acc.x + bias[lane * 2], 0.f);
    float ay = fmaxf(acc.y + bias[lane * 2 + 1], 0.f);
    outb[(size_t)wid * 64 + lane] = ((uint)f2bf(ay) << 16) | (uint)f2bf(ax);
}

// Layer 3: bf16 F=40 segment-sum + bias + log_softmax fused -> d_out (fp32)
__global__ __launch_bounds__(256) void spmm40_lsm(const ushort* __restrict__ sup,
                                                  const int* __restrict__ rsp,
                                                  const uint* __restrict__ edges,
                                                  const float* __restrict__ bias,
                                                  float* __restrict__ out, int n) {
    int wid = blockIdx.x * 4 + (threadIdx.x >> 6);
    int lane = threadIdx.x & 63;
    if (wid >= n) return;
    int k = rsp[wid], e = rsp[wid + 1];
    float acc = 0.f;
    int lf = (lane < 40) ? lane : 39;  // inactive lanes read lane 39 (no OOB)
    if (k < e) {
        const uint4* q4 = (const uint4*)(edges + k);
        uint4 qa = q4[0], qb = q4[1];
        for (; k < e; k += 8) {
            int kn = k + 8;
            int kc = (kn < e) ? kn : k;
            const uint4* n4 = (const uint4*)(edges + kc);
            uint4 na = n4[0], nb = n4[1];
            uint q[8] = {qa.x, qa.y, qa.z, qa.w, qb.x, qb.y, qb.z, qb.w};
            float p[8];
            #pragma unroll
            for (int j = 0; j < 8; ++j) {
                uint us = sup[(size_t)(q[j] & 0xffffu) * 40 + lf];
                p[j] = __uint_as_float(us << 16);
            }
            #pragma unroll
            for (int j = 0; j < 8; ++j)
                acc += p[j] * __uint_as_float(q[j] & 0xffff0000u);
            qa = na; qb = nb;
        }
    }
    float v = (lane < 40) ? acc + bias[lane] : -INFINITY;
    float m = v;
    #pragma unroll
    for (int off = 32; off; off >>= 1) m = fmaxf(m, __shfl_xor(m, off, 64));
    float ex = (lane < 40) ? expf(v - m) : 0.f;
    float s = ex;
    #pragma unroll
    for (int off = 32; off; off >>= 1) s += __shfl_xor(s, off, 64);
    float ls = logf(s);
    if (lane < 40) out[(size_t)wid * 40 + lane] = v - m - ls;
}

// ---------------------------------------------------------------------------
extern "C" void kernel_launch(void* const* d_in, const int* in_sizes, int n_in,
                              void* d_out, int out_size, void* d_ws, size_t ws_size,
                              hipStream_t stream) {
    const float* x   = (const float*)d_in[0];
    const float* ew  = (const float*)d_in[1];
    const float* W1  = (const float*)d_in[2];
    const float* b1  = (const float*)d_in[3];
    const float* W2  = (const float*)d_in[4];
    const float* b2  = (const float*)d_in[5];
    const float* W3  = (const float*)d_in[6];
    const float* b3  = (const float*)d_in[7];
    const int* esrc  = (const int*)d_in[8];
    const int* edst  = (const int*)d_in[9];
    float* out = (float*)d_out;

    char* ws = (char*)d_ws;
    size_t off = 0;
    auto alloc = [&](size_t bytes) {
        size_t cur = off;
        off += (bytes + 255) & ~(size_t)255;
        return cur;
    };
    int* bucket_cnt = (int*)(ws + alloc(256 * sizeof(int)));
    int* bsum    = (int*)(ws + alloc(256 * sizeof(int)));
    int* rsp     = (int*)(ws + alloc((N_NODES + 1) * sizeof(int)));
    uint* edges  = (uint*)(ws + alloc((size_t)E_PAD_MAX * sizeof(uint)));      // 3.8 MB
    int2* staging = (int2*)(ws + alloc((size_t)NBUCK * BUCK_CAP * sizeof(int2))); // 6.4 MB
    ushort* BT1  = (ushort*)(ws + alloc(128 * 256 * 2));
    ushort* BT2  = (ushort*)(ws + alloc(128 * 128 * 2));
    ushort* BT3  = (ushort*)(ws + alloc(64 * 128 * 2));
    char* Sreg   = ws + alloc((size_t)N_NODES * 128 * 2);       // 12.8 MB
    char* Hreg   = ws + alloc((size_t)N_NODES * 128 * 2);       // 12.8 MB
    char* Treg   = ws + alloc((size_t)N_NODES * 128 * 2);       // 12.8 MB

    ushort* supA = (ushort*)Sreg;                  // gemm1 out
    ushort* hA   = (ushort*)Hreg;                  // spmm1 out
    ushort* supB = (ushort*)Treg;                  // gemm2 out
    ushort* hB   = (ushort*)Sreg;                  // spmm2 out (supA dead)
    ushort* sup3 = (ushort*)Treg;                  // gemm3 out bf16 (supB dead)

    int cvtw_blocks = (57344 + 255) / 256;    // 224

    // --- CSR build: memset(1KB), binA, bucket_hist(+cvtw), scan_scatter ---
    hipMemsetAsync(bucket_cnt, 0, 256 * sizeof(int), stream);
    scatter_binA<<<(N_EDGES + EPB_A - 1) / EPB_A, 256, 0, stream>>>(
        esrc, edst, ew, bucket_cnt, staging, N_EDGES);
    bucket_hist_cvtw<<<NBUCK + cvtw_blocks, 256, 0, stream>>>(
        bucket_cnt, staging, bsum, NBUCK, W1, W2, W3, BT1, BT2, BT3);
    scan_scatter<<<NBUCK, 256, 0, stream>>>(bsum, bucket_cnt, staging, rsp,
                                            edges, N_NODES);

    int spmm_blocks = (N_NODES + 3) / 4;     // 12500

    // --- layer 1 (x fp32 converted in gemm staging) ---
    gemm_mfma<2, true, true><<<GEMM_BLOCKS, 256, 0, stream>>>(x, BT1, N_NODES, 256,
                                                              128, supA);
    spmm128b<<<spmm_blocks, 256, 0, stream>>>((const uint*)supA, rsp, edges, b1,
                                              (uint*)hA, N_NODES);
    // --- layer 2 ---
    gemm_mfma<2, true, false><<<GEMM_BLOCKS, 256, 0, stream>>>(hA, BT2, N_NODES, 128,
                                                               128, supB);
    spmm128b<<<spmm_blocks, 256, 0, stream>>>((const uint*)supB, rsp, edges, b2,
                                              (uint*)hB, N_NODES);
    // --- layer 3 ---
    gemm_mfma<1, true, false><<<GEMM_BLOCKS, 256, 0, stream>>>(hB, BT3, N_NODES, 128,
                                                               40, sup3);
    spmm40_lsm<<<spmm_blocks, 256, 0, stream>>>(sup3, rsp, edges, b3, out, N_NODES);
}